// Round 1
// baseline (1567.489 us; speedup 1.0000x reference)
//
#include <hip/hip_runtime.h>

#define S_LEN 2048
#define DH 64
#define TQ 64
#define TK 64
#define NKT (S_LEN / TK)   // 32
#define LDSP 72            // padded LDS row stride in shorts (144 B: 16B-aligned rows, 2-way bank alias only)

typedef __attribute__((ext_vector_type(8))) short short8;
typedef __attribute__((ext_vector_type(4))) short short4v;
typedef __attribute__((ext_vector_type(4))) float float4v;

static __device__ __forceinline__ short f2bf(float x) {
    unsigned u = __builtin_bit_cast(unsigned, x);
    u += 0x7fff + ((u >> 16) & 1);   // RNE to bf16
    return (short)(u >> 16);
}

static __device__ __forceinline__ short8 cvt8(float4v a, float4v b) {
    short8 s;
    s[0] = f2bf(a[0]); s[1] = f2bf(a[1]); s[2] = f2bf(a[2]); s[3] = f2bf(a[3]);
    s[4] = f2bf(b[0]); s[5] = f2bf(b[1]); s[6] = f2bf(b[2]); s[7] = f2bf(b[3]);
    return s;
}

__global__ __launch_bounds__(256, 2) void attn_kernel(
    const float* __restrict__ q,
    const float* __restrict__ k,
    const float* __restrict__ v,
    const int*   __restrict__ mask,
    float* __restrict__ out,    // [64][2048][64]
    float* __restrict__ attn)   // [64][2048][2048]
{
    __shared__ short Qs[TQ * LDSP];
    __shared__ short Ks[TK * LDSP];
    __shared__ short Vt[DH * LDSP];       // transposed V tile: Vt[d][kk]
    __shared__ short Ps[4 * 16 * LDSP];   // per-wave P tile (C-layout -> A-layout round trip)

    const int tid  = threadIdx.x;
    const int wave = tid >> 6;
    const int lane = tid & 63;
    const int l16  = lane & 15;
    const int quad = lane >> 4;

    const int bid = blockIdx.x;
    const int qt  = bid & 31;    // q-tile fastest: blocks sharing (b,h) share K/V in cache
    const int bh  = bid >> 5;
    const int b   = bh >> 4;     // H = 16
    const int q0  = qt * TQ;

    const float* qg = q + ((size_t)bh * S_LEN + q0) * DH;
    const float* kg = k + (size_t)bh * S_LEN * DH;
    const float* vg = v + (size_t)bh * S_LEN * DH;
    const int*   mg = mask + ((size_t)b * S_LEN + q0) * S_LEN;
    float* attng = attn + ((size_t)bh * S_LEN + q0) * (size_t)S_LEN;

    const int qrow_base = wave * 16;  // 16 q-rows per wave

    // ---- stage Q tile (64x64 fp32 -> bf16) ----
    #pragma unroll
    for (int it = 0; it < 2; ++it) {
        int c = tid + it * 256;              // 0..511 chunks of 8 floats
        int row = c >> 3, col8 = (c & 7) << 3;
        const float4v* gp = (const float4v*)(qg + (size_t)row * DH + col8);
        *(short8*)&Qs[row * LDSP + col8] = cvt8(gp[0], gp[1]);
    }

    auto stageK = [&](int kt) {
        #pragma unroll
        for (int it = 0; it < 2; ++it) {
            int c = tid + it * 256;
            int row = c >> 3, col8 = (c & 7) << 3;
            const float4v* gp = (const float4v*)(kg + (size_t)(kt * TK + row) * DH + col8);
            *(short8*)&Ks[row * LDSP + col8] = cvt8(gp[0], gp[1]);
        }
    };

    // ================= PASS 1: row sums of exp(s) =================
    float rs[4] = {0.f, 0.f, 0.f, 0.f};

    for (int kt = 0; kt < NKT; ++kt) {
        __syncthreads();
        stageK(kt);
        __syncthreads();

        short8 afr0 = *(const short8*)&Qs[(qrow_base + l16) * LDSP + quad * 8];
        short8 afr1 = *(const short8*)&Qs[(qrow_base + l16) * LDSP + 32 + quad * 8];

        #pragma unroll
        for (int sub = 0; sub < 4; ++sub) {
            float4v acc = {0.f, 0.f, 0.f, 0.f};
            short8 b0 = *(const short8*)&Ks[(sub * 16 + l16) * LDSP + quad * 8];
            short8 b1 = *(const short8*)&Ks[(sub * 16 + l16) * LDSP + 32 + quad * 8];
            acc = __builtin_amdgcn_mfma_f32_16x16x32_bf16(afr0, b0, acc, 0, 0, 0);
            acc = __builtin_amdgcn_mfma_f32_16x16x32_bf16(afr1, b1, acc, 0, 0, 0);
            int kkg = kt * TK + sub * 16 + l16;
            #pragma unroll
            for (int r = 0; r < 4; ++r) {
                int qrow = qrow_base + quad * 4 + r;
                int m = mg[(size_t)qrow * S_LEN + kkg];
                float p = m ? __expf(acc[r] * 0.125f) : 0.f;
                rs[r] += p;
            }
        }
    }

    // reduce row sums across the 16 lanes of each quad; keep reciprocal
    #pragma unroll
    for (int r = 0; r < 4; ++r) {
        float s = rs[r];
        s += __shfl_xor(s, 1);
        s += __shfl_xor(s, 2);
        s += __shfl_xor(s, 4);
        s += __shfl_xor(s, 8);
        rs[r] = 1.0f / s;
    }

    // ================= PASS 2: write attn + PV =================
    float4v oacc[4];
    #pragma unroll
    for (int i = 0; i < 4; ++i) oacc[i] = (float4v){0.f, 0.f, 0.f, 0.f};

    short* Pw = &Ps[wave * 16 * LDSP];

    for (int kt = 0; kt < NKT; ++kt) {
        __syncthreads();
        stageK(kt);
        // stage V transposed: Vt[d][kk] = V[kk][d], 4x4 micro-tiles
        {
            int kb = tid >> 4, db = tid & 15;
            const float* vbase = vg + (size_t)(kt * TK + kb * 4) * DH + db * 4;
            float4v r0 = *(const float4v*)(vbase + 0 * DH);
            float4v r1 = *(const float4v*)(vbase + 1 * DH);
            float4v r2 = *(const float4v*)(vbase + 2 * DH);
            float4v r3 = *(const float4v*)(vbase + 3 * DH);
            #pragma unroll
            for (int t = 0; t < 4; ++t) {
                int i = (t + tid) & 3;   // rotate write order to spread banks
                short4v sv = { f2bf(r0[i]), f2bf(r1[i]), f2bf(r2[i]), f2bf(r3[i]) };
                *(short4v*)&Vt[(db * 4 + i) * LDSP + kb * 4] = sv;
            }
        }
        __syncthreads();

        short8 afr0 = *(const short8*)&Qs[(qrow_base + l16) * LDSP + quad * 8];
        short8 afr1 = *(const short8*)&Qs[(qrow_base + l16) * LDSP + 32 + quad * 8];

        #pragma unroll
        for (int sub = 0; sub < 4; ++sub) {
            float4v acc = {0.f, 0.f, 0.f, 0.f};
            short8 b0 = *(const short8*)&Ks[(sub * 16 + l16) * LDSP + quad * 8];
            short8 b1 = *(const short8*)&Ks[(sub * 16 + l16) * LDSP + 32 + quad * 8];
            acc = __builtin_amdgcn_mfma_f32_16x16x32_bf16(afr0, b0, acc, 0, 0, 0);
            acc = __builtin_amdgcn_mfma_f32_16x16x32_bf16(afr1, b1, acc, 0, 0, 0);
            int kkl = sub * 16 + l16;
            int kkg = kt * TK + kkl;
            #pragma unroll
            for (int r = 0; r < 4; ++r) {
                int qrow = qrow_base + quad * 4 + r;
                int m = mg[(size_t)qrow * S_LEN + kkg];
                float p = m ? __expf(acc[r] * 0.125f) * rs[r] : 0.f;
                attng[(size_t)qrow * S_LEN + kkg] = p;
                Pw[(quad * 4 + r) * LDSP + kkl] = f2bf(p);
            }
        }
        __syncthreads();  // Ps visible (also keeps Vt stable) before PV frag reads

        #pragma unroll
        for (int ks = 0; ks < 2; ++ks) {
            short8 pa = *(const short8*)&Pw[l16 * LDSP + ks * 32 + quad * 8];
            #pragma unroll
            for (int dsub = 0; dsub < 4; ++dsub) {
                short8 bv = *(const short8*)&Vt[(dsub * 16 + l16) * LDSP + ks * 32 + quad * 8];
                oacc[dsub] = __builtin_amdgcn_mfma_f32_16x16x32_bf16(pa, bv, oacc[dsub], 0, 0, 0);
            }
        }
    }

    // ---- epilogue: store output tile ----
    float* og = out + ((size_t)bh * S_LEN + q0) * DH;
    #pragma unroll
    for (int dsub = 0; dsub < 4; ++dsub) {
        #pragma unroll
        for (int r = 0; r < 4; ++r) {
            og[(size_t)(qrow_base + quad * 4 + r) * DH + dsub * 16 + l16] = oacc[dsub][r];
        }
    }
}

extern "C" void kernel_launch(void* const* d_in, const int* in_sizes, int n_in,
                              void* d_out, int out_size, void* d_ws, size_t ws_size,
                              hipStream_t stream) {
    (void)in_sizes; (void)n_in; (void)out_size; (void)d_ws; (void)ws_size;
    const float* q    = (const float*)d_in[0];
    const float* k    = (const float*)d_in[1];
    const float* v    = (const float*)d_in[2];
    const int*   mask = (const int*)d_in[3];
    float* out  = (float*)d_out;
    float* attn = out + (size_t)4 * 16 * 2048 * 64;   // outputs concatenated: (output, attn)
    attn_kernel<<<dim3(2048), dim3(256), 0, stream>>>(q, k, v, mask, out, attn);
}